// Round 1
// baseline (320.117 us; speedup 1.0000x reference)
//
#include <hip/hip_runtime.h>
#include <math.h>

// Sparsemax over rows: out = max(z - tau, 0), tau s.t. sum(max(z - tau, 0)) = 1.
// One block per row; row (4096 fp32) held entirely in registers (16/thread).
//
// Key observation: f(zmax-1) >= 1, so the root tau lies in [zmax-1, zmax] and
// ONLY elements with z > zmax-1 ever contribute to f(tau). For Gaussian data
// that is ~15-30 of 4096 elements. So instead of 12 block-wide reduction
// iterations (24 barriers + 72 chained shuffles per row = the measured stall),
// we compact the candidates into LDS once and let EVERY thread redundantly
// solve the same bisection + exact refinement over the shared candidates in
// registers: zero barriers, zero cross-lane ops in the solve.
//
// Paths (block-uniform branches on candidate count m):
//   m <= 32   : candidates in registers, fully unrolled solve   (~99% of rows)
//   m <= 1024 : candidates looped from LDS (broadcast reads)    (~1% of rows)
//   m >  1024 : original block-wide bisection fallback          (never for this data)

constexpr int S   = 4096;
constexpr int TPB = 256;
constexpr int VPT = S / TPB;   // 16 values per thread
constexpr int NW  = TPB / 64;  // 4 waves per block
constexpr int CAP = 1024;      // LDS candidate capacity
constexpr int MC  = 32;        // register-path candidate capacity

#define NEGBIG (-1e30f)

__global__ __launch_bounds__(TPB) void sparsemax_kernel(
    const float* __restrict__ scores,
    const int*   __restrict__ mask,
    float*       __restrict__ out)
{
    const int row  = blockIdx.x;
    const int tid  = threadIdx.x;
    const int lane = tid & 63;
    const int wid  = tid >> 6;

    const float* srow = scores + (size_t)row * S;
    const int*   mrow = mask   + (size_t)row * S;
    float*       orow = out    + (size_t)row * S;

    float z[VPT];
    #pragma unroll
    for (int ch = 0; ch < VPT / 4; ++ch) {
        const int idx = ch * (TPB * 4) + tid * 4;
        const float4 s4 = *reinterpret_cast<const float4*>(srow + idx);
        const int4   m4 = *reinterpret_cast<const int4*>(mrow + idx);
        z[ch * 4 + 0] = m4.x ? s4.x : NEGBIG;
        z[ch * 4 + 1] = m4.y ? s4.y : NEGBIG;
        z[ch * 4 + 2] = m4.z ? s4.z : NEGBIG;
        z[ch * 4 + 3] = m4.w ? s4.w : NEGBIG;
    }

    __shared__ float red[NW];
    __shared__ float red2[NW];
    __shared__ __align__(16) float cand[CAP];
    __shared__ int cnt;

    // init candidate padding + counter (covered by the zmax barrier below)
    #pragma unroll
    for (int j = 0; j < CAP / TPB; ++j) cand[j * TPB + tid] = NEGBIG;
    if (tid == 0) cnt = 0;

    // ---- row max (the only cross-thread reduction on the fast path) ----
    float mx = z[0];
    #pragma unroll
    for (int j = 1; j < VPT; ++j) mx = fmaxf(mx, z[j]);
    #pragma unroll
    for (int o = 1; o < 64; o <<= 1) mx = fmaxf(mx, __shfl_xor(mx, o, 64));
    if (lane == 0) red[wid] = mx;
    __syncthreads();
    const float zmax = fmaxf(fmaxf(red[0], red[1]), fmaxf(red[2], red[3]));
    const float thr  = zmax - 1.0f;   // root tau is in [thr, zmax]

    // ---- compact candidates (z > thr) into LDS ----
    #pragma unroll
    for (int j = 0; j < VPT; ++j) {
        if (z[j] > thr) {
            const int p = atomicAdd(&cnt, 1);
            if (p < CAP) cand[p] = z[j];
        }
    }
    __syncthreads();
    const int m = cnt;   // >= 1 (zmax itself is always a candidate)

    float tau;
    if (m <= MC) {
        // ---- path A: candidates in registers, barrier-free redundant solve ----
        float cr[MC];
        #pragma unroll
        for (int i = 0; i < MC; i += 4) {
            const float4 c4 = *reinterpret_cast<const float4*>(&cand[i]);
            cr[i + 0] = c4.x; cr[i + 1] = c4.y; cr[i + 2] = c4.z; cr[i + 3] = c4.w;
        }
        float lo = thr, hi = zmax;
        #pragma unroll 1
        for (int it = 0; it < 12; ++it) {
            const float mid = 0.5f * (lo + hi);
            float f0 = 0.f, f1 = 0.f, f2 = 0.f, f3 = 0.f;
            #pragma unroll
            for (int i = 0; i < MC; i += 4) {
                f0 += fmaxf(cr[i + 0] - mid, 0.f);
                f1 += fmaxf(cr[i + 1] - mid, 0.f);
                f2 += fmaxf(cr[i + 2] - mid, 0.f);
                f3 += fmaxf(cr[i + 3] - mid, 0.f);
            }
            if (((f0 + f1) + (f2 + f3)) > 1.0f) lo = mid; else hi = mid;
        }
        const float tc = 0.5f * (lo + hi);
        float s = 0.f, k = 0.f;
        #pragma unroll
        for (int i = 0; i < MC; ++i) {
            if (cr[i] > tc) { s += cr[i]; k += 1.f; }
        }
        tau = (s - 1.0f) / k;
    } else if (m <= CAP) {
        // ---- path B: loop candidates from LDS (broadcast reads), no barriers ----
        const int m4 = (m + 3) & ~3;   // padding entries are NEGBIG
        float lo = thr, hi = zmax;
        #pragma unroll 1
        for (int it = 0; it < 12; ++it) {
            const float mid = 0.5f * (lo + hi);
            float f0 = 0.f, f1 = 0.f, f2 = 0.f, f3 = 0.f;
            for (int i = 0; i < m4; i += 4) {
                const float4 c4 = *reinterpret_cast<const float4*>(&cand[i]);
                f0 += fmaxf(c4.x - mid, 0.f);
                f1 += fmaxf(c4.y - mid, 0.f);
                f2 += fmaxf(c4.z - mid, 0.f);
                f3 += fmaxf(c4.w - mid, 0.f);
            }
            if (((f0 + f1) + (f2 + f3)) > 1.0f) lo = mid; else hi = mid;
        }
        const float tc = 0.5f * (lo + hi);
        float s = 0.f, k = 0.f;
        for (int i = 0; i < m4; i += 4) {
            const float4 c4 = *reinterpret_cast<const float4*>(&cand[i]);
            if (c4.x > tc) { s += c4.x; k += 1.f; }
            if (c4.y > tc) { s += c4.y; k += 1.f; }
            if (c4.z > tc) { s += c4.z; k += 1.f; }
            if (c4.w > tc) { s += c4.w; k += 1.f; }
        }
        tau = (s - 1.0f) / k;
    } else {
        // ---- path C: original block-wide bisection fallback (m > CAP) ----
        float lo = thr, hi = zmax;
        #pragma unroll 1
        for (int it = 0; it < 12; ++it) {
            const float mid = 0.5f * (lo + hi);
            float f = 0.f;
            #pragma unroll
            for (int j = 0; j < VPT; ++j) f += fmaxf(z[j] - mid, 0.f);
            #pragma unroll
            for (int o = 1; o < 64; o <<= 1) f += __shfl_xor(f, o, 64);
            __syncthreads();
            if (lane == 0) red[wid] = f;
            __syncthreads();
            f = (red[0] + red[1]) + (red[2] + red[3]);
            if (f > 1.0f) lo = mid; else hi = mid;
        }
        const float tc = 0.5f * (lo + hi);
        float s = 0.f, k = 0.f;
        #pragma unroll
        for (int j = 0; j < VPT; ++j) {
            if (z[j] > tc) { s += z[j]; k += 1.f; }
        }
        #pragma unroll
        for (int o = 1; o < 64; o <<= 1) {
            s += __shfl_xor(s, o, 64);
            k += __shfl_xor(k, o, 64);
        }
        __syncthreads();
        if (lane == 0) { red[wid] = s; red2[wid] = k; }
        __syncthreads();
        s = (red[0] + red[1]) + (red[2] + red[3]);
        k = (red2[0] + red2[1]) + (red2[2] + red2[3]);
        if (k < 0.5f) { k = 1.0f; s = zmax; }   // unreachable guard
        tau = (s - 1.0f) / k;
    }

    // ---- write out ----
    #pragma unroll
    for (int ch = 0; ch < VPT / 4; ++ch) {
        const int idx = ch * (TPB * 4) + tid * 4;
        float4 o4;
        o4.x = fmaxf(z[ch * 4 + 0] - tau, 0.0f);
        o4.y = fmaxf(z[ch * 4 + 1] - tau, 0.0f);
        o4.z = fmaxf(z[ch * 4 + 2] - tau, 0.0f);
        o4.w = fmaxf(z[ch * 4 + 3] - tau, 0.0f);
        *reinterpret_cast<float4*>(orow + idx) = o4;
    }
}

extern "C" void kernel_launch(void* const* d_in, const int* in_sizes, int n_in,
                              void* d_out, int out_size, void* d_ws, size_t ws_size,
                              hipStream_t stream) {
    const float* scores = (const float*)d_in[0];
    const int*   mask   = (const int*)d_in[1];
    float*       out    = (float*)d_out;
    const int B = in_sizes[0] / S;  // 8192
    sparsemax_kernel<<<dim3(B), dim3(TPB), 0, stream>>>(scores, mask, out);
}

// Round 2
// 308.171 us; speedup vs baseline: 1.0388x; 1.0388x over previous
//
#include <hip/hip_runtime.h>
#include <math.h>

// Sparsemax over rows: out = max(z - tau, 0), tau s.t. sum(max(z - tau, 0)) = 1.
// One block per row; row (4096 fp32) held entirely in registers (16/thread).
//
// Solve strategy: f(zmax-1) >= 1, so tau lies in [zmax-1, zmax] and only
// elements with z > zmax-1 (~13 of 4096 for this data) matter. Those are
// compacted into LDS once. Then tau is computed in CLOSED FORM (no bisection,
// no sort): for candidate c_i, with n_i = #{j: c_j >= c_i} and
// s_i = sum{c_j >= c_i}, the support condition is 1 + n_i*c_i > s_i, and
// tau = max over valid i of (s_i - 1)/n_i. ((cs_k-1)/k is increasing over
// valid sorted positions: increment from k to k+1 is
// [1 + k*z_{k+1} - cs_k]/(k(k+1)), positive iff position k+1 is valid.
// Tie groups share validity, so '>=' counting is exact.)
//
// Per-row cost: 1 max-reduce + ~m LDS broadcast reads on m threads + 1
// max-reduce. 3 barriers total. Exact tau (absmax ~1e-6 vs 9.8e-4 for the
// old 12-step bisection).

constexpr int S   = 4096;
constexpr int TPB = 256;
constexpr int VPT = S / TPB;   // 16 values per thread
constexpr int NW  = TPB / 64;  // 4 waves per block
constexpr int CAP = 1024;      // LDS candidate capacity (fallback beyond)

#define NEGBIG (-1e30f)

__global__ __launch_bounds__(TPB) void sparsemax_kernel(
    const float* __restrict__ scores,
    const int*   __restrict__ mask,
    float*       __restrict__ out)
{
    const int row  = blockIdx.x;
    const int tid  = threadIdx.x;
    const int lane = tid & 63;
    const int wid  = tid >> 6;

    const float* srow = scores + (size_t)row * S;
    const int*   mrow = mask   + (size_t)row * S;
    float*       orow = out    + (size_t)row * S;

    float z[VPT];
    #pragma unroll
    for (int ch = 0; ch < VPT / 4; ++ch) {
        const int idx = ch * (TPB * 4) + tid * 4;
        const float4 s4 = *reinterpret_cast<const float4*>(srow + idx);
        const int4   m4 = *reinterpret_cast<const int4*>(mrow + idx);
        z[ch * 4 + 0] = m4.x ? s4.x : NEGBIG;
        z[ch * 4 + 1] = m4.y ? s4.y : NEGBIG;
        z[ch * 4 + 2] = m4.z ? s4.z : NEGBIG;
        z[ch * 4 + 3] = m4.w ? s4.w : NEGBIG;
    }

    __shared__ float red[NW];
    __shared__ float red2[NW];
    __shared__ float cand[CAP];
    __shared__ int cnt;
    if (tid == 0) cnt = 0;

    // ---- row max ----
    float mx = z[0];
    #pragma unroll
    for (int j = 1; j < VPT; ++j) mx = fmaxf(mx, z[j]);
    #pragma unroll
    for (int o = 1; o < 64; o <<= 1) mx = fmaxf(mx, __shfl_xor(mx, o, 64));
    if (lane == 0) red[wid] = mx;
    __syncthreads();                                   // A (also covers cnt=0)
    const float zmax = fmaxf(fmaxf(red[0], red[1]), fmaxf(red[2], red[3]));
    const float thr  = zmax - 1.0f;   // tau is in [thr, zmax]

    // ---- compact candidates (z > thr) into LDS ----
    #pragma unroll
    for (int j = 0; j < VPT; ++j) {
        if (z[j] > thr) {
            const int p = atomicAdd(&cnt, 1);
            if (p < CAP) cand[p] = z[j];
        }
    }
    __syncthreads();                                   // B (also frees red[])
    const int m = cnt;   // >= 1 (zmax is always a candidate)

    float tau;
    if (m <= CAP) {
        // ---- closed-form tau over candidates, no sort, no bisection ----
        float t = NEGBIG;
        for (int i = tid; i < m; i += TPB) {           // threads >= m skip
            const float ci = cand[i];
            float n = 0.0f, s = 0.0f;
            for (int j = 0; j < m; ++j) {              // same j all lanes: LDS broadcast
                const float cj = cand[j];
                if (cj >= ci) { n += 1.0f; s += cj; }
            }
            if (1.0f + n * ci > s) t = fmaxf(t, (s - 1.0f) / n);
        }
        #pragma unroll
        for (int o = 1; o < 64; o <<= 1) t = fmaxf(t, __shfl_xor(t, o, 64));
        if (lane == 0) red[wid] = t;
        __syncthreads();                               // C
        tau = fmaxf(fmaxf(red[0], red[1]), fmaxf(red[2], red[3]));
    } else {
        // ---- fallback: block-wide bisection (m > CAP; unreachable for this data) ----
        float lo = thr, hi = zmax;
        #pragma unroll 1
        for (int it = 0; it < 24; ++it) {
            const float mid = 0.5f * (lo + hi);
            float f = 0.0f;
            #pragma unroll
            for (int j = 0; j < VPT; ++j) f += fmaxf(z[j] - mid, 0.0f);
            #pragma unroll
            for (int o = 1; o < 64; o <<= 1) f += __shfl_xor(f, o, 64);
            __syncthreads();
            if (lane == 0) red[wid] = f;
            __syncthreads();
            f = (red[0] + red[1]) + (red[2] + red[3]);
            if (f > 1.0f) lo = mid; else hi = mid;
        }
        const float tc = 0.5f * (lo + hi);
        float s = 0.0f, k = 0.0f;
        #pragma unroll
        for (int j = 0; j < VPT; ++j) {
            if (z[j] > tc) { s += z[j]; k += 1.0f; }
        }
        #pragma unroll
        for (int o = 1; o < 64; o <<= 1) {
            s += __shfl_xor(s, o, 64);
            k += __shfl_xor(k, o, 64);
        }
        __syncthreads();
        if (lane == 0) { red[wid] = s; red2[wid] = k; }
        __syncthreads();
        s = (red[0] + red[1]) + (red[2] + red[3]);
        k = (red2[0] + red2[1]) + (red2[2] + red2[3]);
        if (k < 0.5f) { k = 1.0f; s = zmax; }          // unreachable guard
        tau = (s - 1.0f) / k;
    }

    // ---- write out ----
    #pragma unroll
    for (int ch = 0; ch < VPT / 4; ++ch) {
        const int idx = ch * (TPB * 4) + tid * 4;
        float4 o4;
        o4.x = fmaxf(z[ch * 4 + 0] - tau, 0.0f);
        o4.y = fmaxf(z[ch * 4 + 1] - tau, 0.0f);
        o4.z = fmaxf(z[ch * 4 + 2] - tau, 0.0f);
        o4.w = fmaxf(z[ch * 4 + 3] - tau, 0.0f);
        *reinterpret_cast<float4*>(orow + idx) = o4;
    }
}

extern "C" void kernel_launch(void* const* d_in, const int* in_sizes, int n_in,
                              void* d_out, int out_size, void* d_ws, size_t ws_size,
                              hipStream_t stream) {
    const float* scores = (const float*)d_in[0];
    const int*   mask   = (const int*)d_in[1];
    float*       out    = (float*)d_out;
    const int B = in_sizes[0] / S;  // 8192
    sparsemax_kernel<<<dim3(B), dim3(TPB), 0, stream>>>(scores, mask, out);
}